// Round 1
// baseline (50664.032 us; speedup 1.0000x reference)
//
#include <hip/hip_runtime.h>
#include <hip/hip_bf16.h>

// ---------------- constants ----------------
// T=2048, IN=1024, OUT=4096, MEM=256, M=8192, HG=128, HL=256
static constexpr int kT    = 2048;
static constexpr int kIN   = 1024;
static constexpr int kOUT  = 4096;
static constexpr int kMROW = 8192;
static constexpr int kOUT_ELEMS = 2048 * 4096;   // output 0 size

typedef _Float16 half2_t __attribute__((ext_vector_type(2)));

__device__ __forceinline__ unsigned pack_h2(float a, float b) {
  half2_t h{(_Float16)a, (_Float16)b};
  return __builtin_bit_cast(unsigned, h);
}
__device__ __forceinline__ float fdot2u(unsigned a, unsigned b, float c) {
  return __builtin_amdgcn_fdot2(__builtin_bit_cast(half2_t, a),
                                __builtin_bit_cast(half2_t, b), c, false);
}
__device__ __forceinline__ float sigm(float x) {
  return 1.f / (1.f + __expf(-x));
}
__device__ __forceinline__ float tanh_f(float x) {
  float ax = fabsf(x);
  float e = __expf(-2.f * ax);
  float r = (1.f - e) / (1.f + e);
  return x < 0.f ? -r : r;
}

// ---------------- K0: prep (weight concat / bias sums / fp16 Whh pack) ----------------
__global__ __launch_bounds__(256) void prep_kernel(
    const float* __restrict__ enc_Wih, const float* __restrict__ enc_bih,
    const float* __restrict__ cenc_Wih, const float* __restrict__ cenc_bih,
    const float* __restrict__ l0_Whh, const float* __restrict__ l1_Whh,
    const float* __restrict__ l0_bih, const float* __restrict__ l0_bhh,
    const float* __restrict__ l1_bih, const float* __restrict__ l1_bhh,
    float* __restrict__ wcat, float* __restrict__ bcat,
    float* __restrict__ bias0, float* __restrict__ bias1,
    unsigned* __restrict__ wprep) {
  int idx0 = blockIdx.x * blockDim.x + threadIdx.x;
  int stride = gridDim.x * blockDim.x;
  // wcat [768][1024] = [enc_Wih dir0 ; cenc_Wih dir0]
  for (int i = idx0; i < 768 * 1024; i += stride) {
    int r = i >> 10, cc = i & 1023;
    wcat[i] = (r < 384) ? enc_Wih[r * 1024 + cc] : cenc_Wih[(r - 384) * 1024 + cc];
  }
  for (int i = idx0; i < 768; i += stride)
    bcat[i] = (i < 384) ? enc_bih[i] : cenc_bih[i - 384];
  for (int i = idx0; i < 2048; i += stride) {
    bias0[i] = l0_bih[i] + l0_bhh[i];
    bias1[i] = l1_bih[i] + l1_bhh[i];
  }
  // wprep [ld][e<128][row<1024] = half2(Whh[ld][row][2e], Whh[ld][row][2e+1])
  for (int i = idx0; i < 2 * 2 * 128 * 1024; i += stride) {
    int row = i & 1023;
    int e = (i >> 10) & 127;
    int ld = i >> 17;  // layer*2 + dir
    const float* W = (ld < 2 ? l0_Whh : l1_Whh) + (ld & 1) * 1024 * 256;
    wprep[i] = pack_h2(W[row * 256 + 2 * e], W[row * 256 + 2 * e + 1]);
  }
}

// ---------------- fp32 tiled GEMM: C[M][N] = A[M][K] * B[N][K]^T + bias[N] ----------------
__global__ __launch_bounds__(256) void gemm_bt(
    const float* __restrict__ A, const float* __restrict__ B,
    const float* __restrict__ bias, float* __restrict__ C,
    int M, int N, int K) {
  __shared__ float As[16][68];
  __shared__ float Bs[16][68];
  int tid = threadIdx.x;
  int tx = tid & 15, ty = tid >> 4;
  int m0 = blockIdx.y * 64, n0 = blockIdx.x * 64;
  int lr = tid >> 2;         // 0..63
  int lc = (tid & 3) << 2;   // 0,4,8,12
  float acc[4][4] = {};
  const float* Ap = A + (long)(m0 + lr) * K + lc;
  const float* Bp = B + (long)(n0 + lr) * K + lc;
  for (int k0 = 0; k0 < K; k0 += 16) {
    float4 a4 = *(const float4*)(Ap + k0);
    float4 b4 = *(const float4*)(Bp + k0);
    __syncthreads();
    As[lc + 0][lr] = a4.x; As[lc + 1][lr] = a4.y; As[lc + 2][lr] = a4.z; As[lc + 3][lr] = a4.w;
    Bs[lc + 0][lr] = b4.x; Bs[lc + 1][lr] = b4.y; Bs[lc + 2][lr] = b4.z; Bs[lc + 3][lr] = b4.w;
    __syncthreads();
#pragma unroll
    for (int kk = 0; kk < 16; kk++) {
      float4 ra = *(const float4*)&As[kk][ty << 2];
      float4 rb = *(const float4*)&Bs[kk][tx << 2];
      float av[4] = {ra.x, ra.y, ra.z, ra.w};
      float bv[4] = {rb.x, rb.y, rb.z, rb.w};
#pragma unroll
      for (int i = 0; i < 4; i++)
#pragma unroll
        for (int jj = 0; jj < 4; jj++)
          acc[i][jj] += av[i] * bv[jj];
    }
  }
#pragma unroll
  for (int i = 0; i < 4; i++) {
    int m = m0 + (ty << 2) + i;
#pragma unroll
    for (int jj = 0; jj < 4; jj++) {
      int n = n0 + (tx << 2) + jj;
      C[(long)m * N + n] = acc[i][jj] + (bias ? bias[n] : 0.f);
    }
  }
}

// ---------------- K3: GRU chains ----------------
// block 0: enc forward (2048 steps)   -> u[0:128]
// block 1: cenc forward (2048 steps)  -> c_memory[0:128]
// block 2: enc backward single step   -> u[128:256]
// block 3: cenc backward single step  -> c_memory[128:256]
__global__ __launch_bounds__(384) void gru_kernel(
    const float* __restrict__ xgg,   // [T][768]  (cols 0..383 enc, 384..767 cenc)
    const float* __restrict__ c_in,  // [T][1024]
    const float* __restrict__ enc_Wih, const float* __restrict__ enc_Whh,
    const float* __restrict__ enc_bih, const float* __restrict__ enc_bhh,
    const float* __restrict__ cenc_Wih, const float* __restrict__ cenc_Whh,
    const float* __restrict__ cenc_bih, const float* __restrict__ cenc_bhh,
    float* __restrict__ u_out, float* __restrict__ cmem_out) {
  int b = blockIdx.x, j = threadIdx.x;
  __shared__ float h_lds[128];
  __shared__ float zb[128], ndot[128], nxg[128];
  if (b < 2) {
    const float* Whh = (b == 0) ? enc_Whh : cenc_Whh;
    const float* bhh = (b == 0) ? enc_bhh : cenc_bhh;
    const float* xp = xgg + b * 384;
    float w[128];
#pragma unroll
    for (int e = 0; e < 128; e++) w[e] = Whh[j * 128 + e];
    float bh = bhh[j];
    if (j < 128) h_lds[j] = 0.f;
    float hreg = 0.f;
    __syncthreads();
    float xgc = xp[j];
    for (int t = 0; t < kT; t++) {
      float xgn = 0.f;
      if (t + 1 < kT) xgn = xp[(t + 1) * 768 + j];
      float dot = bh;  // includes bhh for this row
#pragma unroll
      for (int e4 = 0; e4 < 32; e4++) {
        float4 h4 = *(const float4*)&h_lds[e4 * 4];
        dot += w[4 * e4 + 0] * h4.x;
        dot += w[4 * e4 + 1] * h4.y;
        dot += w[4 * e4 + 2] * h4.z;
        dot += w[4 * e4 + 3] * h4.w;
      }
      if (j >= 256) { ndot[j - 256] = dot; nxg[j - 256] = xgc; }
      else if (j >= 128) { zb[j - 128] = xgc + dot; }
      __syncthreads();
      if (j < 128) {
        float r = sigm(xgc + dot);
        float z = sigm(zb[j]);
        float n = tanh_f(nxg[j] + r * ndot[j]);
        hreg = (1.f - z) * n + z * hreg;
        h_lds[j] = hreg;
      }
      __syncthreads();
      xgc = xgn;
    }
    if (j < 128) {
      if (b == 0) u_out[j] = hreg; else cmem_out[j] = hreg;
    }
  } else {
    // backward direction, single step from zero state at t = T-1
    const float* Wih = ((b == 2) ? enc_Wih : cenc_Wih) + 384 * 1024;
    const float* bih = ((b == 2) ? enc_bih : cenc_bih) + 384;
    const float* bhh = ((b == 2) ? enc_bhh : cenc_bhh) + 384;
    const float* crow = c_in + (long)(kT - 1) * 1024;
    float acc = bih[j];
    for (int k = 0; k < 1024; k += 4) {
      float4 cv = *(const float4*)&crow[k];
      float4 wv = *(const float4*)&Wih[j * 1024 + k];
      acc += cv.x * wv.x + cv.y * wv.y + cv.z * wv.z + cv.w * wv.w;
    }
    float bh = bhh[j];
    if (j >= 256) { ndot[j - 256] = bh; nxg[j - 256] = acc; }
    else if (j >= 128) { zb[j - 128] = acc + bh; }
    __syncthreads();
    if (j < 128) {
      float r = sigm(acc + bh);
      float z = sigm(zb[j]);
      float n = tanh_f(nxg[j] + r * ndot[j]);
      float h = (1.f - z) * n;
      if (b == 2) u_out[128 + j] = h; else cmem_out[128 + j] = h;
    }
  }
}

// ---------------- attention ----------------
__global__ __launch_bounds__(256) void attn_dots(
    const float* __restrict__ mem, const float* __restrict__ u, float* __restrict__ d) {
  __shared__ float us[256];
  int tid = threadIdx.x;
  us[tid] = u[tid];
  __syncthreads();
  int g = tid >> 3, l8 = tid & 7;
  int row = blockIdx.x * 32 + g;
  const float* mr = mem + (long)row * 256 + l8 * 32;
  float p = 0.f;
#pragma unroll
  for (int k = 0; k < 32; k += 4) {
    float4 m4 = *(const float4*)&mr[k];
    p += m4.x * us[l8 * 32 + k] + m4.y * us[l8 * 32 + k + 1] +
         m4.z * us[l8 * 32 + k + 2] + m4.w * us[l8 * 32 + k + 3];
  }
  p += __shfl_down(p, 4);
  p += __shfl_down(p, 2);
  p += __shfl_down(p, 1);
  if (l8 == 0) d[row] = p;
}

__global__ __launch_bounds__(1024) void attn_soft(
    const float* __restrict__ d, float* __restrict__ p, float* __restrict__ h_acc) {
  __shared__ float red[1024];
  int tid = threadIdx.x;
  float v[8];
  float mx = -1e30f;
#pragma unroll
  for (int i = 0; i < 8; i++) { v[i] = d[tid * 8 + i]; mx = fmaxf(mx, v[i]); }
  red[tid] = mx; __syncthreads();
  for (int s = 512; s > 0; s >>= 1) {
    if (tid < s) red[tid] = fmaxf(red[tid], red[tid + s]);
    __syncthreads();
  }
  mx = red[0]; __syncthreads();
  float sm = 0.f; float e[8];
#pragma unroll
  for (int i = 0; i < 8; i++) { e[i] = __expf(v[i] - mx); sm += e[i]; }
  red[tid] = sm; __syncthreads();
  for (int s = 512; s > 0; s >>= 1) {
    if (tid < s) red[tid] += red[tid + s];
    __syncthreads();
  }
  float rz = 1.f / red[0];
#pragma unroll
  for (int i = 0; i < 8; i++) p[tid * 8 + i] = e[i] * rz;
  if (tid < 256) h_acc[tid] = 0.f;   // re-zero every launch (stream-ordered before attn_h)
}

__global__ __launch_bounds__(256) void attn_h(
    const float* __restrict__ mem, const float* __restrict__ p, float* __restrict__ h_acc) {
  int tid = threadIdx.x;
  int r0 = blockIdx.x * 128;
  float acc = 0.f;
  for (int i = 0; i < 128; i++) acc += p[r0 + i] * mem[(long)(r0 + i) * 256 + tid];
  atomicAdd(&h_acc[tid], acc);
}

__global__ __launch_bounds__(128) void attn_o(
    const float* __restrict__ u, const float* __restrict__ h_acc,
    const float* __restrict__ know_W, const float* __restrict__ know_b,
    float* __restrict__ o) {
  __shared__ float uh[256];
  int tid = threadIdx.x;
  uh[tid] = u[tid] + h_acc[tid];
  uh[128 + tid] = u[128 + tid] + h_acc[128 + tid];
  __syncthreads();
  int row = blockIdx.x * 128 + tid;
  float acc = know_b[row];
  for (int k = 0; k < 256; k += 4) {
    float4 w4 = *(const float4*)&know_W[row * 256 + k];
    acc += w4.x * uh[k] + w4.y * uh[k + 1] + w4.z * uh[k + 2] + w4.w * uh[k + 3];
  }
  o[row] = acc;
}

__global__ __launch_bounds__(128) void attn_ov(
    const float* __restrict__ o, const float* __restrict__ Wih0, float* __restrict__ ov) {
  int row = blockIdx.x * 128 + threadIdx.x;
  float acc = 0.f;
  for (int k = 0; k < 1024; k += 4) {
    float4 w4 = *(const float4*)&Wih0[(long)row * 1024 + k];
    float4 o4 = *(const float4*)&o[k];
    acc += w4.x * o4.x + w4.y * o4.y + w4.z * o4.z + w4.w * o4.w;
  }
  ov[row] = acc;
}

// ---------------- LSTM chain (one direction per block) ----------------
// gates rows: i[0:256) f[256:512) g[512:768) o[768:1024)
// thread j owns rows j and 512+j. Whh packed fp16: 96 half2 in regs + 32 half2 in LDS per row.
__global__ __launch_bounds__(512) void lstm_kernel(
    const unsigned* __restrict__ wprep,  // this layer: [dir][128][1024] half2-packed
    const float* __restrict__ xg,        // [T][2048], col = dir*1024 + row (bih+bhh folded in)
    const float* __restrict__ extra,     // [2048] (o @ Wih^T) or nullptr
    float* __restrict__ out) {           // [T][512], fwd cols 0:256, bwd 256:512
  constexpr int RP = 96;  // reg half2 per row
  constexpr int LP = 32;  // lds half2 per row
  int dir = blockIdx.x, j = threadIdx.x;
  __shared__ unsigned wl[LP * 1024];   // 128 KB
  __shared__ float2 fo[256];
  __shared__ unsigned h2v[128];
  const unsigned* wp = wprep + dir * (128 * 1024);
  for (int i = j; i < LP * 1024; i += 512) wl[i] = wp[RP * 1024 + i];
  unsigned wA[RP], wB[RP];
#pragma unroll
  for (int e = 0; e < RP; e++) {
    wA[e] = wp[e * 1024 + j];
    wB[e] = wp[e * 1024 + 512 + j];
  }
  float exA = 0.f, exB = 0.f;
  if (extra) { exA = extra[dir * 1024 + j]; exB = extra[dir * 1024 + 512 + j]; }
  if (j < 128) h2v[j] = 0u;
  float cst = 0.f;
  __syncthreads();
  const float* xp = xg + dir * 1024;
  const int t0 = dir ? (kT - 1) : 0;
  const int dt = dir ? -1 : 1;
  float xgA = xp[(long)t0 * 2048 + j] + exA;
  float xgB = xp[(long)t0 * 2048 + 512 + j] + exB;
  for (int s = 0; s < kT; ++s) {
    int t = t0 + s * dt;
    float xgAn = 0.f, xgBn = 0.f;
    if (s + 1 < kT) {
      int tn = t + dt;
      xgAn = xp[(long)tn * 2048 + j];
      xgBn = xp[(long)tn * 2048 + 512 + j];
    }
    float accA = xgA, accB = xgB;
#pragma unroll
    for (int g = 0; g < 32; ++g) {
      uint4 hh = *(const uint4*)&h2v[g * 4];
      if (g < 24) {
        accA = fdot2u(wA[4 * g + 0], hh.x, accA);
        accA = fdot2u(wA[4 * g + 1], hh.y, accA);
        accA = fdot2u(wA[4 * g + 2], hh.z, accA);
        accA = fdot2u(wA[4 * g + 3], hh.w, accA);
        accB = fdot2u(wB[4 * g + 0], hh.x, accB);
        accB = fdot2u(wB[4 * g + 1], hh.y, accB);
        accB = fdot2u(wB[4 * g + 2], hh.z, accB);
        accB = fdot2u(wB[4 * g + 3], hh.w, accB);
      } else {
        int e = (g - 24) * 4;
        accA = fdot2u(wl[(e + 0) * 1024 + j], hh.x, accA);
        accA = fdot2u(wl[(e + 1) * 1024 + j], hh.y, accA);
        accA = fdot2u(wl[(e + 2) * 1024 + j], hh.z, accA);
        accA = fdot2u(wl[(e + 3) * 1024 + j], hh.w, accA);
        accB = fdot2u(wl[(e + 0) * 1024 + 512 + j], hh.x, accB);
        accB = fdot2u(wl[(e + 1) * 1024 + 512 + j], hh.y, accB);
        accB = fdot2u(wl[(e + 2) * 1024 + 512 + j], hh.z, accB);
        accB = fdot2u(wl[(e + 3) * 1024 + 512 + j], hh.w, accB);
      }
    }
    float aA = sigm(accA);                                   // i (j<256) or f (j>=256)
    float aB = (j < 256) ? tanh_f(accB) : sigm(accB);        // g or o
    if (j >= 256) fo[j - 256] = make_float2(aA, aB);         // publish f,o
    __syncthreads();
    if (j < 256) {
      float2 f_o = fo[j];
      cst = f_o.x * cst + aA * aB;                           // c = f*c + i*g
      float h = f_o.y * tanh_f(cst);                         // h = o*tanh(c)
      out[(long)t * 512 + dir * 256 + j] = h;
      float hx = __shfl_xor(h, 1);
      if (!(j & 1)) h2v[j >> 1] = pack_h2(h, hx);
    }
    __syncthreads();
    xgA = xgAn + exA;
    xgB = xgBn + exB;
  }
}

// ---------------- final row softmax ----------------
__global__ __launch_bounds__(256) void softmax_rows(
    const float* __restrict__ logits, float* __restrict__ outp) {
  int t = blockIdx.x, tid = threadIdx.x;
  __shared__ float red[256];
  const float* lr = logits + (long)t * 4096;
  float v[16];
  float mx = -1e30f;
#pragma unroll
  for (int i = 0; i < 16; i++) { v[i] = lr[tid + 256 * i]; mx = fmaxf(mx, v[i]); }
  red[tid] = mx; __syncthreads();
  for (int s = 128; s > 0; s >>= 1) {
    if (tid < s) red[tid] = fmaxf(red[tid], red[tid + s]);
    __syncthreads();
  }
  mx = red[0]; __syncthreads();
  float sm = 0.f;
#pragma unroll
  for (int i = 0; i < 16; i++) { v[i] = __expf(v[i] - mx); sm += v[i]; }
  red[tid] = sm; __syncthreads();
  for (int s = 128; s > 0; s >>= 1) {
    if (tid < s) red[tid] += red[tid + s];
    __syncthreads();
  }
  float rz = 1.f / red[0];
#pragma unroll
  for (int i = 0; i < 16; i++) outp[(long)t * 4096 + tid + 256 * i] = v[i] * rz;
}

// ---------------- launch ----------------
extern "C" void kernel_launch(void* const* d_in, const int* in_sizes, int n_in,
                              void* d_out, int out_size, void* d_ws, size_t ws_size,
                              hipStream_t stream) {
  const float* c        = (const float*)d_in[0];
  const float* memory   = (const float*)d_in[1];
  const float* enc_Wih  = (const float*)d_in[2];
  const float* enc_Whh  = (const float*)d_in[3];
  const float* enc_bih  = (const float*)d_in[4];
  const float* enc_bhh  = (const float*)d_in[5];
  const float* cenc_Wih = (const float*)d_in[6];
  const float* cenc_Whh = (const float*)d_in[7];
  const float* cenc_bih = (const float*)d_in[8];
  const float* cenc_bhh = (const float*)d_in[9];
  const float* know_W   = (const float*)d_in[10];
  const float* know_b   = (const float*)d_in[11];
  const float* l0_Wih   = (const float*)d_in[12];
  const float* l0_Whh   = (const float*)d_in[13];
  const float* l0_bih   = (const float*)d_in[14];
  const float* l0_bhh   = (const float*)d_in[15];
  const float* l1_Wih   = (const float*)d_in[16];
  const float* l1_Whh   = (const float*)d_in[17];
  const float* l1_bih   = (const float*)d_in[18];
  const float* l1_bhh   = (const float*)d_in[19];
  const float* out_W    = (const float*)d_in[20];
  const float* out_b    = (const float*)d_in[21];

  float* ws = (float*)d_ws;
  float* outp = (float*)d_out;

  // ws layout (floats); logits aliases the first regions (all dead by then)
  float* xgg   = ws;                  // 1,572,864   [T][768]
  float* cW    = ws + 1572864;        // 4,194,304   [T][2048]
  float* wcat  = ws + 5767168;        //   786,432
  float* l0out = ws + 6553600;        // 1,048,576   [T][512]
  float* xg1   = ws + 7602176;        // 4,194,304   [T][2048]
  unsigned* wprep = (unsigned*)(ws + 11796480);  // 524,288 u32
  float* bcat  = ws + 12320768;       // 768
  float* bias0 = ws + 12321536;       // 2048
  float* bias1 = ws + 12323584;       // 2048
  float* u_vec = ws + 12325632;       // 256
  float* d_att = ws + 12325888;       // 8192
  float* p_att = ws + 12334080;       // 8192
  float* h_acc = ws + 12342272;       // 256
  float* o_vec = ws + 12342528;       // 1024
  float* ov    = ws + 12343552;       // 2048
  float* l1out = ws + 12345600;       // 1,048,576   (end: 13,394,176 floats = 53.6 MB)
  float* logits = ws;                 // 8,388,608   aliases xgg/cW/wcat/l0out/part of xg1

  // K0: preprocessing
  prep_kernel<<<512, 256, 0, stream>>>(enc_Wih, enc_bih, cenc_Wih, cenc_bih,
                                       l0_Whh, l1_Whh, l0_bih, l0_bhh, l1_bih, l1_bhh,
                                       wcat, bcat, bias0, bias1, wprep);
  // K1: GRU forward input projections (enc dir0 + cenc dir0)
  gemm_bt<<<dim3(768 / 64, 2048 / 64), 256, 0, stream>>>(c, wcat, bcat, xgg, 2048, 768, 1024);
  // K2: lstm0 projection of c (o-part added later as rank-1 via ov)
  gemm_bt<<<dim3(2048 / 64, 2048 / 64), 256, 0, stream>>>(c, l0_Wih, bias0, cW, 2048, 2048, 1024);
  // K3: GRU chains (fwd full, bwd single-step) -> u, c_memory
  gru_kernel<<<4, 384, 0, stream>>>(xgg, c, enc_Wih, enc_Whh, enc_bih, enc_bhh,
                                    cenc_Wih, cenc_Whh, cenc_bih, cenc_bhh,
                                    u_vec, outp + kOUT_ELEMS);
  // K4..K7: attention + o + rank-1 projection
  attn_dots<<<256, 256, 0, stream>>>(memory, u_vec, d_att);
  attn_soft<<<1, 1024, 0, stream>>>(d_att, p_att, h_acc);
  attn_h<<<64, 256, 0, stream>>>(memory, p_att, h_acc);
  attn_o<<<8, 128, 0, stream>>>(u_vec, h_acc, know_W, know_b, o_vec);
  attn_ov<<<16, 128, 0, stream>>>(o_vec, l0_Wih, ov);
  // K8: lstm0 chains
  lstm_kernel<<<2, 512, 0, stream>>>(wprep, cW, ov, l0out);
  // K9: lstm1 input projection
  gemm_bt<<<dim3(2048 / 64, 2048 / 64), 256, 0, stream>>>(l0out, l1_Wih, bias1, xg1, 2048, 2048, 512);
  // K10: lstm1 chains
  lstm_kernel<<<2, 512, 0, stream>>>(wprep + 2 * 131072, xg1, nullptr, l1out);
  // K11: output projection
  gemm_bt<<<dim3(4096 / 64, 2048 / 64), 256, 0, stream>>>(l1out, out_W, out_b, logits, 2048, 4096, 512);
  // K12: row softmax -> d_out
  softmax_rows<<<2048, 256, 0, stream>>>(logits, outp);
}

// Round 2
// 22843.835 us; speedup vs baseline: 2.2178x; 2.2178x over previous
//
#include <hip/hip_runtime.h>
#include <hip/hip_bf16.h>

// ---------------- constants ----------------
static constexpr int kT    = 2048;
static constexpr int kOUT_ELEMS = 2048 * 4096;   // output 0 size

typedef _Float16 half2_t __attribute__((ext_vector_type(2)));

__device__ __forceinline__ unsigned pack_h2(float a, float b) {
  half2_t h{(_Float16)a, (_Float16)b};
  return __builtin_bit_cast(unsigned, h);
}
__device__ __forceinline__ float fdot2u(unsigned a, unsigned b, float c) {
  return __builtin_amdgcn_fdot2(__builtin_bit_cast(half2_t, a),
                                __builtin_bit_cast(half2_t, b), c, false);
}
__device__ __forceinline__ float sigm(float x) {
  return 1.f / (1.f + __expf(-x));
}
__device__ __forceinline__ float tanh_f(float x) {
  float ax = fabsf(x);
  float e = __expf(-2.f * ax);
  float r = (1.f - e) / (1.f + e);
  return x < 0.f ? -r : r;
}

// ---------------- K0: prep (weight concat / bias sums / fp16 Whh pack) ----------------
__global__ __launch_bounds__(256) void prep_kernel(
    const float* __restrict__ enc_Wih, const float* __restrict__ enc_bih,
    const float* __restrict__ cenc_Wih, const float* __restrict__ cenc_bih,
    const float* __restrict__ l0_Whh, const float* __restrict__ l1_Whh,
    const float* __restrict__ l0_bih, const float* __restrict__ l0_bhh,
    const float* __restrict__ l1_bih, const float* __restrict__ l1_bhh,
    float* __restrict__ wcat, float* __restrict__ bcat,
    float* __restrict__ bias0, float* __restrict__ bias1,
    unsigned* __restrict__ wprep) {
  int idx0 = blockIdx.x * blockDim.x + threadIdx.x;
  int stride = gridDim.x * blockDim.x;
  for (int i = idx0; i < 768 * 1024; i += stride) {
    int r = i >> 10, cc = i & 1023;
    wcat[i] = (r < 384) ? enc_Wih[r * 1024 + cc] : cenc_Wih[(r - 384) * 1024 + cc];
  }
  for (int i = idx0; i < 768; i += stride)
    bcat[i] = (i < 384) ? enc_bih[i] : cenc_bih[i - 384];
  for (int i = idx0; i < 2048; i += stride) {
    bias0[i] = l0_bih[i] + l0_bhh[i];
    bias1[i] = l1_bih[i] + l1_bhh[i];
  }
  // wprep [ld][e<128][row<1024] = half2(Whh[ld][row][2e], Whh[ld][row][2e+1])
  for (int i = idx0; i < 2 * 2 * 128 * 1024; i += stride) {
    int row = i & 1023;
    int e = (i >> 10) & 127;
    int ld = i >> 17;  // layer*2 + dir
    const float* W = (ld < 2 ? l0_Whh : l1_Whh) + (ld & 1) * 1024 * 256;
    wprep[i] = pack_h2(W[row * 256 + 2 * e], W[row * 256 + 2 * e + 1]);
  }
}

// ---------------- fp32 tiled GEMM: C[M][N] = A[M][K] * B[N][K]^T + bias[N] ----------------
__global__ __launch_bounds__(256) void gemm_bt(
    const float* __restrict__ A, const float* __restrict__ B,
    const float* __restrict__ bias, float* __restrict__ C,
    int M, int N, int K) {
  __shared__ float As[16][68];
  __shared__ float Bs[16][68];
  int tid = threadIdx.x;
  int tx = tid & 15, ty = tid >> 4;
  int m0 = blockIdx.y * 64, n0 = blockIdx.x * 64;
  int lr = tid >> 2;         // 0..63
  int lc = (tid & 3) << 2;   // 0,4,8,12
  float acc[4][4] = {};
  const float* Ap = A + (long)(m0 + lr) * K + lc;
  const float* Bp = B + (long)(n0 + lr) * K + lc;
  for (int k0 = 0; k0 < K; k0 += 16) {
    float4 a4 = *(const float4*)(Ap + k0);
    float4 b4 = *(const float4*)(Bp + k0);
    __syncthreads();
    As[lc + 0][lr] = a4.x; As[lc + 1][lr] = a4.y; As[lc + 2][lr] = a4.z; As[lc + 3][lr] = a4.w;
    Bs[lc + 0][lr] = b4.x; Bs[lc + 1][lr] = b4.y; Bs[lc + 2][lr] = b4.z; Bs[lc + 3][lr] = b4.w;
    __syncthreads();
#pragma unroll
    for (int kk = 0; kk < 16; kk++) {
      float4 ra = *(const float4*)&As[kk][ty << 2];
      float4 rb = *(const float4*)&Bs[kk][tx << 2];
      float av[4] = {ra.x, ra.y, ra.z, ra.w};
      float bv[4] = {rb.x, rb.y, rb.z, rb.w};
#pragma unroll
      for (int i = 0; i < 4; i++)
#pragma unroll
        for (int jj = 0; jj < 4; jj++)
          acc[i][jj] += av[i] * bv[jj];
    }
  }
#pragma unroll
  for (int i = 0; i < 4; i++) {
    int m = m0 + (ty << 2) + i;
#pragma unroll
    for (int jj = 0; jj < 4; jj++) {
      int n = n0 + (tx << 2) + jj;
      C[(long)m * N + n] = acc[i][jj] + (bias ? bias[n] : 0.f);
    }
  }
}

// ---------------- K3: GRU chains ----------------
__global__ __launch_bounds__(384, 2) void gru_kernel(
    const float* __restrict__ xgg,   // [T][768]  (cols 0..383 enc, 384..767 cenc)
    const float* __restrict__ c_in,  // [T][1024]
    const float* __restrict__ enc_Wih, const float* __restrict__ enc_Whh,
    const float* __restrict__ enc_bih, const float* __restrict__ enc_bhh,
    const float* __restrict__ cenc_Wih, const float* __restrict__ cenc_Whh,
    const float* __restrict__ cenc_bih, const float* __restrict__ cenc_bhh,
    float* __restrict__ u_out, float* __restrict__ cmem_out) {
  int b = blockIdx.x, j = threadIdx.x;
  __shared__ float h_lds[128];
  __shared__ float zb[128], ndot[128], nxg[128];
  if (b < 2) {
    const float* Whh = (b == 0) ? enc_Whh : cenc_Whh;
    const float* bhh = (b == 0) ? enc_bhh : cenc_bhh;
    const float* xp = xgg + b * 384;
    float w[128];
#pragma unroll
    for (int e = 0; e < 128; e++) w[e] = Whh[j * 128 + e];
    float bh = bhh[j];
    if (j < 128) h_lds[j] = 0.f;
    float hreg = 0.f;
    __syncthreads();
    float xgc = xp[j];
    for (int t = 0; t < kT; t++) {
      float xgn = 0.f;
      if (t + 1 < kT) xgn = xp[(t + 1) * 768 + j];
      float dot = bh;
#pragma unroll
      for (int e4 = 0; e4 < 32; e4++) {
        float4 h4 = *(const float4*)&h_lds[e4 * 4];
        dot += w[4 * e4 + 0] * h4.x;
        dot += w[4 * e4 + 1] * h4.y;
        dot += w[4 * e4 + 2] * h4.z;
        dot += w[4 * e4 + 3] * h4.w;
      }
      if (j >= 256) { ndot[j - 256] = dot; nxg[j - 256] = xgc; }
      else if (j >= 128) { zb[j - 128] = xgc + dot; }
      __syncthreads();
      if (j < 128) {
        float r = sigm(xgc + dot);
        float z = sigm(zb[j]);
        float n = tanh_f(nxg[j] + r * ndot[j]);
        hreg = (1.f - z) * n + z * hreg;
        h_lds[j] = hreg;
      }
      __syncthreads();
      xgc = xgn;
    }
    if (j < 128) {
      if (b == 0) u_out[j] = hreg; else cmem_out[j] = hreg;
    }
  } else {
    // backward direction, single step from zero state at t = T-1
    const float* Wih = ((b == 2) ? enc_Wih : cenc_Wih) + 384 * 1024;
    const float* bih = ((b == 2) ? enc_bih : cenc_bih) + 384;
    const float* bhh = ((b == 2) ? enc_bhh : cenc_bhh) + 384;
    const float* crow = c_in + (long)(kT - 1) * 1024;
    float acc = bih[j];
    for (int k = 0; k < 1024; k += 4) {
      float4 cv = *(const float4*)&crow[k];
      float4 wv = *(const float4*)&Wih[j * 1024 + k];
      acc += cv.x * wv.x + cv.y * wv.y + cv.z * wv.z + cv.w * wv.w;
    }
    float bh = bhh[j];
    if (j >= 256) { ndot[j - 256] = bh; nxg[j - 256] = acc; }
    else if (j >= 128) { zb[j - 128] = acc + bh; }
    __syncthreads();
    if (j < 128) {
      float r = sigm(acc + bh);
      float z = sigm(zb[j]);
      float n = tanh_f(nxg[j] + r * ndot[j]);
      float h = (1.f - z) * n;
      if (b == 2) u_out[128 + j] = h; else cmem_out[128 + j] = h;
    }
  }
}

// ---------------- attention ----------------
__global__ __launch_bounds__(256) void attn_dots(
    const float* __restrict__ mem, const float* __restrict__ u, float* __restrict__ d) {
  __shared__ float us[256];
  int tid = threadIdx.x;
  us[tid] = u[tid];
  __syncthreads();
  int g = tid >> 3, l8 = tid & 7;
  int row = blockIdx.x * 32 + g;
  const float* mr = mem + (long)row * 256 + l8 * 32;
  float p = 0.f;
#pragma unroll
  for (int k = 0; k < 32; k += 4) {
    float4 m4 = *(const float4*)&mr[k];
    p += m4.x * us[l8 * 32 + k] + m4.y * us[l8 * 32 + k + 1] +
         m4.z * us[l8 * 32 + k + 2] + m4.w * us[l8 * 32 + k + 3];
  }
  p += __shfl_down(p, 4);
  p += __shfl_down(p, 2);
  p += __shfl_down(p, 1);
  if (l8 == 0) d[row] = p;
}

__global__ __launch_bounds__(1024) void attn_soft(
    const float* __restrict__ d, float* __restrict__ p, float* __restrict__ h_acc) {
  __shared__ float red[1024];
  int tid = threadIdx.x;
  float v[8];
  float mx = -1e30f;
#pragma unroll
  for (int i = 0; i < 8; i++) { v[i] = d[tid * 8 + i]; mx = fmaxf(mx, v[i]); }
  red[tid] = mx; __syncthreads();
  for (int s = 512; s > 0; s >>= 1) {
    if (tid < s) red[tid] = fmaxf(red[tid], red[tid + s]);
    __syncthreads();
  }
  mx = red[0]; __syncthreads();
  float sm = 0.f; float e[8];
#pragma unroll
  for (int i = 0; i < 8; i++) { e[i] = __expf(v[i] - mx); sm += e[i]; }
  red[tid] = sm; __syncthreads();
  for (int s = 512; s > 0; s >>= 1) {
    if (tid < s) red[tid] += red[tid + s];
    __syncthreads();
  }
  float rz = 1.f / red[0];
#pragma unroll
  for (int i = 0; i < 8; i++) p[tid * 8 + i] = e[i] * rz;
  if (tid < 256) h_acc[tid] = 0.f;   // re-zero every launch (stream-ordered before attn_h)
}

__global__ __launch_bounds__(256) void attn_h(
    const float* __restrict__ mem, const float* __restrict__ p, float* __restrict__ h_acc) {
  int tid = threadIdx.x;
  int r0 = blockIdx.x * 128;
  float acc = 0.f;
  for (int i = 0; i < 128; i++) acc += p[r0 + i] * mem[(long)(r0 + i) * 256 + tid];
  atomicAdd(&h_acc[tid], acc);
}

__global__ __launch_bounds__(128) void attn_o(
    const float* __restrict__ u, const float* __restrict__ h_acc,
    const float* __restrict__ know_W, const float* __restrict__ know_b,
    float* __restrict__ o) {
  __shared__ float uh[256];
  int tid = threadIdx.x;
  uh[tid] = u[tid] + h_acc[tid];
  uh[128 + tid] = u[128 + tid] + h_acc[128 + tid];
  __syncthreads();
  int row = blockIdx.x * 128 + tid;
  float acc = know_b[row];
  for (int k = 0; k < 256; k += 4) {
    float4 w4 = *(const float4*)&know_W[row * 256 + k];
    acc += w4.x * uh[k] + w4.y * uh[k + 1] + w4.z * uh[k + 2] + w4.w * uh[k + 3];
  }
  o[row] = acc;
}

__global__ __launch_bounds__(128) void attn_ov(
    const float* __restrict__ o, const float* __restrict__ Wih0, float* __restrict__ ov) {
  int row = blockIdx.x * 128 + threadIdx.x;
  float acc = 0.f;
  for (int k = 0; k < 1024; k += 4) {
    float4 w4 = *(const float4*)&Wih0[(long)row * 1024 + k];
    float4 o4 = *(const float4*)&o[k];
    acc += w4.x * o4.x + w4.y * o4.y + w4.z * o4.z + w4.w * o4.w;
  }
  ov[row] = acc;
}

// fold X[t][c] += v[c] (rank-1 input projection of o into the lstm0 gate buffer)
__global__ __launch_bounds__(256) void add_vec_rows(
    float* __restrict__ X, const float* __restrict__ v) {
  int t = blockIdx.x;
  int c = threadIdx.x * 8;
  float* xp = X + (long)t * 2048 + c;
  float4 a = *(const float4*)(xp);
  float4 b = *(const float4*)(xp + 4);
  float4 va = *(const float4*)(v + c);
  float4 vb = *(const float4*)(v + c + 4);
  a.x += va.x; a.y += va.y; a.z += va.z; a.w += va.w;
  b.x += vb.x; b.y += vb.y; b.z += vb.z; b.w += vb.w;
  *(float4*)(xp) = a;
  *(float4*)(xp + 4) = b;
}

// ---------------- LSTM chain (one direction per block, 256 threads) ----------------
// Thread j owns gate rows {j, 256+j, 512+j, 768+j} = (i,f,g,o) for h-element j.
// Weights fp16-packed: 96 half2/row in VGPRs (384 regs), 32 half2/row in LDS.
// 1 wave/SIMD (launch_bounds(256,1)) -> VGPR cap 512, no spill.
__global__ __launch_bounds__(256, 1) void lstm_kernel(
    const unsigned* __restrict__ wprep,  // this layer: [dir][128][1024] half2-packed
    const float* __restrict__ xg,        // [T][2048], col = dir*1024 + row (biases folded)
    float* __restrict__ out) {           // [T][512], fwd cols 0:256, bwd 256:512
  constexpr int RP = 96;   // half2 per row in regs
  constexpr int LP = 32;   // half2 per row in LDS
  int dir = blockIdx.x, j = threadIdx.x;   // j in [0,256)
  __shared__ unsigned wl[LP * 1024];       // 128 KB, [e][row]
  __shared__ unsigned h2v[2][128];         // packed h double buffer
  const unsigned* wp = wprep + dir * (128 * 1024);
  for (int i = j; i < LP * 1024; i += 256) wl[i] = wp[RP * 1024 + i];
  unsigned w0[RP], w1[RP], w2[RP], w3[RP];
#pragma unroll
  for (int e = 0; e < RP; e++) {
    w0[e] = wp[e * 1024 + j];
    w1[e] = wp[e * 1024 + 256 + j];
    w2[e] = wp[e * 1024 + 512 + j];
    w3[e] = wp[e * 1024 + 768 + j];
  }
  if (j < 128) h2v[0][j] = 0u;
  float cst = 0.f;
  __syncthreads();
  const float* xp = xg + (dir ? 1024 : 0);
  const int t0 = dir ? (kT - 1) : 0;
  const int dt = dir ? -1 : 1;
  {
    const float* xr = xp + (long)t0 * 2048;
    // prefetched current-step gates
  }
  float x0 = xp[(long)t0 * 2048 + j];
  float x1 = xp[(long)t0 * 2048 + 256 + j];
  float x2 = xp[(long)t0 * 2048 + 512 + j];
  float x3 = xp[(long)t0 * 2048 + 768 + j];
  for (int s = 0; s < kT; ++s) {
    int t = t0 + s * dt;
    float n0 = 0.f, n1 = 0.f, n2 = 0.f, n3 = 0.f;
    if (s + 1 < kT) {
      const float* xn = xp + (long)(t + dt) * 2048;
      n0 = xn[j]; n1 = xn[256 + j]; n2 = xn[512 + j]; n3 = xn[768 + j];
    }
    float a0 = x0, a1 = x1, a2 = x2, a3 = x3;
    const unsigned* hb = h2v[s & 1];
#pragma unroll
    for (int e4 = 0; e4 < 32; ++e4) {
      uint4 hh = *(const uint4*)&hb[e4 * 4];
      unsigned hq0 = hh.x, hq1 = hh.y, hq2 = hh.z, hq3 = hh.w;
#pragma unroll
      for (int q = 0; q < 4; ++q) {
        int e = e4 * 4 + q;
        unsigned hq = (q == 0) ? hq0 : (q == 1) ? hq1 : (q == 2) ? hq2 : hq3;
        if (e < RP) {
          a0 = fdot2u(w0[e], hq, a0);
          a1 = fdot2u(w1[e], hq, a1);
          a2 = fdot2u(w2[e], hq, a2);
          a3 = fdot2u(w3[e], hq, a3);
        } else {
          int o = (e - RP) * 1024 + j;
          a0 = fdot2u(wl[o], hq, a0);
          a1 = fdot2u(wl[o + 256], hq, a1);
          a2 = fdot2u(wl[o + 512], hq, a2);
          a3 = fdot2u(wl[o + 768], hq, a3);
        }
      }
    }
    float ig = sigm(a0);
    float fg = sigm(a1);
    float gg = tanh_f(a2);
    float og = sigm(a3);
    cst = fg * cst + ig * gg;
    float h = og * tanh_f(cst);
    out[(long)t * 512 + dir * 256 + j] = h;
    float hx = __shfl_xor(h, 1);
    if (!(j & 1)) h2v[(s + 1) & 1][j >> 1] = pack_h2(h, hx);
    __syncthreads();
    x0 = n0; x1 = n1; x2 = n2; x3 = n3;
  }
}

// ---------------- final row softmax ----------------
__global__ __launch_bounds__(256) void softmax_rows(
    const float* __restrict__ logits, float* __restrict__ outp) {
  int t = blockIdx.x, tid = threadIdx.x;
  __shared__ float red[256];
  const float* lr = logits + (long)t * 4096;
  float v[16];
  float mx = -1e30f;
#pragma unroll
  for (int i = 0; i < 16; i++) { v[i] = lr[tid + 256 * i]; mx = fmaxf(mx, v[i]); }
  red[tid] = mx; __syncthreads();
  for (int s = 128; s > 0; s >>= 1) {
    if (tid < s) red[tid] = fmaxf(red[tid], red[tid + s]);
    __syncthreads();
  }
  mx = red[0]; __syncthreads();
  float sm = 0.f;
#pragma unroll
  for (int i = 0; i < 16; i++) { v[i] = __expf(v[i] - mx); sm += v[i]; }
  red[tid] = sm; __syncthreads();
  for (int s = 128; s > 0; s >>= 1) {
    if (tid < s) red[tid] += red[tid + s];
    __syncthreads();
  }
  float rz = 1.f / red[0];
#pragma unroll
  for (int i = 0; i < 16; i++) outp[(long)t * 4096 + tid + 256 * i] = v[i] * rz;
}

// ---------------- launch ----------------
extern "C" void kernel_launch(void* const* d_in, const int* in_sizes, int n_in,
                              void* d_out, int out_size, void* d_ws, size_t ws_size,
                              hipStream_t stream) {
  const float* c        = (const float*)d_in[0];
  const float* memory   = (const float*)d_in[1];
  const float* enc_Wih  = (const float*)d_in[2];
  const float* enc_Whh  = (const float*)d_in[3];
  const float* enc_bih  = (const float*)d_in[4];
  const float* enc_bhh  = (const float*)d_in[5];
  const float* cenc_Wih = (const float*)d_in[6];
  const float* cenc_Whh = (const float*)d_in[7];
  const float* cenc_bih = (const float*)d_in[8];
  const float* cenc_bhh = (const float*)d_in[9];
  const float* know_W   = (const float*)d_in[10];
  const float* know_b   = (const float*)d_in[11];
  const float* l0_Wih   = (const float*)d_in[12];
  const float* l0_Whh   = (const float*)d_in[13];
  const float* l0_bih   = (const float*)d_in[14];
  const float* l0_bhh   = (const float*)d_in[15];
  const float* l1_Wih   = (const float*)d_in[16];
  const float* l1_Whh   = (const float*)d_in[17];
  const float* l1_bih   = (const float*)d_in[18];
  const float* l1_bhh   = (const float*)d_in[19];
  const float* out_W    = (const float*)d_in[20];
  const float* out_b    = (const float*)d_in[21];

  float* ws = (float*)d_ws;
  float* outp = (float*)d_out;

  float* xgg   = ws;                  // 1,572,864   [T][768]
  float* cW    = ws + 1572864;        // 4,194,304   [T][2048]
  float* wcat  = ws + 5767168;        //   786,432
  float* l0out = ws + 6553600;        // 1,048,576   [T][512]
  float* xg1   = ws + 7602176;        // 4,194,304   [T][2048]
  unsigned* wprep = (unsigned*)(ws + 11796480);  // 524,288 u32
  float* bcat  = ws + 12320768;       // 768
  float* bias0 = ws + 12321536;       // 2048
  float* bias1 = ws + 12323584;       // 2048
  float* u_vec = ws + 12325632;       // 256
  float* d_att = ws + 12325888;       // 8192
  float* p_att = ws + 12334080;       // 8192
  float* h_acc = ws + 12342272;       // 256
  float* o_vec = ws + 12342528;       // 1024
  float* ov    = ws + 12343552;       // 2048
  float* l1out = ws + 12345600;       // 1,048,576
  float* logits = ws;                 // 8,388,608   aliases xgg/cW/wcat/l0out/part of xg1

  prep_kernel<<<512, 256, 0, stream>>>(enc_Wih, enc_bih, cenc_Wih, cenc_bih,
                                       l0_Whh, l1_Whh, l0_bih, l0_bhh, l1_bih, l1_bhh,
                                       wcat, bcat, bias0, bias1, wprep);
  gemm_bt<<<dim3(768 / 64, 2048 / 64), 256, 0, stream>>>(c, wcat, bcat, xgg, 2048, 768, 1024);
  gemm_bt<<<dim3(2048 / 64, 2048 / 64), 256, 0, stream>>>(c, l0_Wih, bias0, cW, 2048, 2048, 1024);
  gru_kernel<<<4, 384, 0, stream>>>(xgg, c, enc_Wih, enc_Whh, enc_bih, enc_bhh,
                                    cenc_Wih, cenc_Whh, cenc_bih, cenc_bhh,
                                    u_vec, outp + kOUT_ELEMS);
  attn_dots<<<256, 256, 0, stream>>>(memory, u_vec, d_att);
  attn_soft<<<1, 1024, 0, stream>>>(d_att, p_att, h_acc);
  attn_h<<<64, 256, 0, stream>>>(memory, p_att, h_acc);
  attn_o<<<8, 128, 0, stream>>>(u_vec, h_acc, know_W, know_b, o_vec);
  attn_ov<<<16, 128, 0, stream>>>(o_vec, l0_Wih, ov);
  add_vec_rows<<<2048, 256, 0, stream>>>(cW, ov);
  lstm_kernel<<<2, 256, 0, stream>>>(wprep, cW, l0out);
  gemm_bt<<<dim3(2048 / 64, 2048 / 64), 256, 0, stream>>>(l0out, l1_Wih, bias1, xg1, 2048, 2048, 512);
  lstm_kernel<<<2, 256, 0, stream>>>(wprep + 2 * 131072, xg1, l1out);
  gemm_bt<<<dim3(4096 / 64, 2048 / 64), 256, 0, stream>>>(l1out, out_W, out_b, logits, 2048, 4096, 512);
  softmax_rows<<<2048, 256, 0, stream>>>(logits, outp);
}

// Round 3
// 14670.093 us; speedup vs baseline: 3.4536x; 1.5572x over previous
//
#include <hip/hip_runtime.h>
#include <hip/hip_bf16.h>

// ---------------- constants ----------------
static constexpr int kT    = 2048;
static constexpr int kOUT_ELEMS = 2048 * 4096;   // output 0 size

typedef _Float16 half2_t __attribute__((ext_vector_type(2)));

__device__ __forceinline__ unsigned pack_h2(float a, float b) {
  half2_t h{(_Float16)a, (_Float16)b};
  return __builtin_bit_cast(unsigned, h);
}
__device__ __forceinline__ float fdot2u(unsigned a, unsigned b, float c) {
  return __builtin_amdgcn_fdot2(__builtin_bit_cast(half2_t, a),
                                __builtin_bit_cast(half2_t, b), c, false);
}
// Force a value to live in an AGPR (explicit accvgpr write/read; "a" = AGPR class)
__device__ __forceinline__ unsigned to_agpr(unsigned v) {
  unsigned a;
  asm("v_accvgpr_write_b32 %0, %1" : "=a"(a) : "v"(v));
  return a;
}
__device__ __forceinline__ unsigned from_agpr(unsigned a) {
  unsigned v;
  asm("v_accvgpr_read_b32 %0, %1" : "=v"(v) : "a"(a));
  return v;
}
__device__ __forceinline__ float sigm(float x) {
  return 1.f / (1.f + __expf(-x));
}
__device__ __forceinline__ float tanh_f(float x) {
  float ax = fabsf(x);
  float e = __expf(-2.f * ax);
  float r = (1.f - e) / (1.f + e);
  return x < 0.f ? -r : r;
}

// ---------------- K0: prep (weight concat / bias sums / fp16 Whh pack) ----------------
__global__ __launch_bounds__(256) void prep_kernel(
    const float* __restrict__ enc_Wih, const float* __restrict__ enc_bih,
    const float* __restrict__ cenc_Wih, const float* __restrict__ cenc_bih,
    const float* __restrict__ l0_Whh, const float* __restrict__ l1_Whh,
    const float* __restrict__ l0_bih, const float* __restrict__ l0_bhh,
    const float* __restrict__ l1_bih, const float* __restrict__ l1_bhh,
    float* __restrict__ wcat, float* __restrict__ bcat,
    float* __restrict__ bias0, float* __restrict__ bias1,
    unsigned* __restrict__ wprep) {
  int idx0 = blockIdx.x * blockDim.x + threadIdx.x;
  int stride = gridDim.x * blockDim.x;
  for (int i = idx0; i < 768 * 1024; i += stride) {
    int r = i >> 10, cc = i & 1023;
    wcat[i] = (r < 384) ? enc_Wih[r * 1024 + cc] : cenc_Wih[(r - 384) * 1024 + cc];
  }
  for (int i = idx0; i < 768; i += stride)
    bcat[i] = (i < 384) ? enc_bih[i] : cenc_bih[i - 384];
  for (int i = idx0; i < 2048; i += stride) {
    bias0[i] = l0_bih[i] + l0_bhh[i];
    bias1[i] = l1_bih[i] + l1_bhh[i];
  }
  // wprep [ld][e<128][row<1024] = half2(Whh[ld][row][2e], Whh[ld][row][2e+1])
  for (int i = idx0; i < 2 * 2 * 128 * 1024; i += stride) {
    int row = i & 1023;
    int e = (i >> 10) & 127;
    int ld = i >> 17;  // layer*2 + dir
    const float* W = (ld < 2 ? l0_Whh : l1_Whh) + (ld & 1) * 1024 * 256;
    wprep[i] = pack_h2(W[row * 256 + 2 * e], W[row * 256 + 2 * e + 1]);
  }
}

// ---------------- fp32 tiled GEMM: C[M][N] = A[M][K] * B[N][K]^T + bias[N] ----------------
__global__ __launch_bounds__(256) void gemm_bt(
    const float* __restrict__ A, const float* __restrict__ B,
    const float* __restrict__ bias, float* __restrict__ C,
    int M, int N, int K) {
  __shared__ float As[16][68];
  __shared__ float Bs[16][68];
  int tid = threadIdx.x;
  int tx = tid & 15, ty = tid >> 4;
  int m0 = blockIdx.y * 64, n0 = blockIdx.x * 64;
  int lr = tid >> 2;         // 0..63
  int lc = (tid & 3) << 2;   // 0,4,8,12
  float acc[4][4] = {};
  const float* Ap = A + (long)(m0 + lr) * K + lc;
  const float* Bp = B + (long)(n0 + lr) * K + lc;
  for (int k0 = 0; k0 < K; k0 += 16) {
    float4 a4 = *(const float4*)(Ap + k0);
    float4 b4 = *(const float4*)(Bp + k0);
    __syncthreads();
    As[lc + 0][lr] = a4.x; As[lc + 1][lr] = a4.y; As[lc + 2][lr] = a4.z; As[lc + 3][lr] = a4.w;
    Bs[lc + 0][lr] = b4.x; Bs[lc + 1][lr] = b4.y; Bs[lc + 2][lr] = b4.z; Bs[lc + 3][lr] = b4.w;
    __syncthreads();
#pragma unroll
    for (int kk = 0; kk < 16; kk++) {
      float4 ra = *(const float4*)&As[kk][ty << 2];
      float4 rb = *(const float4*)&Bs[kk][tx << 2];
      float av[4] = {ra.x, ra.y, ra.z, ra.w};
      float bv[4] = {rb.x, rb.y, rb.z, rb.w};
#pragma unroll
      for (int i = 0; i < 4; i++)
#pragma unroll
        for (int jj = 0; jj < 4; jj++)
          acc[i][jj] += av[i] * bv[jj];
    }
  }
#pragma unroll
  for (int i = 0; i < 4; i++) {
    int m = m0 + (ty << 2) + i;
#pragma unroll
    for (int jj = 0; jj < 4; jj++) {
      int n = n0 + (tx << 2) + jj;
      C[(long)m * N + n] = acc[i][jj] + (bias ? bias[n] : 0.f);
    }
  }
}

// ---------------- K3: GRU chains ----------------
__global__ __launch_bounds__(384, 2) void gru_kernel(
    const float* __restrict__ xgg,   // [T][768]  (cols 0..383 enc, 384..767 cenc)
    const float* __restrict__ c_in,  // [T][1024]
    const float* __restrict__ enc_Wih, const float* __restrict__ enc_Whh,
    const float* __restrict__ enc_bih, const float* __restrict__ enc_bhh,
    const float* __restrict__ cenc_Wih, const float* __restrict__ cenc_Whh,
    const float* __restrict__ cenc_bih, const float* __restrict__ cenc_bhh,
    float* __restrict__ u_out, float* __restrict__ cmem_out) {
  int b = blockIdx.x, j = threadIdx.x;
  __shared__ float h_lds[128];
  __shared__ float zb[128], ndot[128], nxg[128];
  if (b < 2) {
    const float* Whh = (b == 0) ? enc_Whh : cenc_Whh;
    const float* bhh = (b == 0) ? enc_bhh : cenc_bhh;
    const float* xp = xgg + b * 384;
    float w[128];
#pragma unroll
    for (int e = 0; e < 128; e++) w[e] = Whh[j * 128 + e];
    float bh = bhh[j];
    if (j < 128) h_lds[j] = 0.f;
    float hreg = 0.f;
    __syncthreads();
    float xgc = xp[j];
    for (int t = 0; t < kT; t++) {
      float xgn = 0.f;
      if (t + 1 < kT) xgn = xp[(t + 1) * 768 + j];
      float dot = bh;
#pragma unroll
      for (int e4 = 0; e4 < 32; e4++) {
        float4 h4 = *(const float4*)&h_lds[e4 * 4];
        dot += w[4 * e4 + 0] * h4.x;
        dot += w[4 * e4 + 1] * h4.y;
        dot += w[4 * e4 + 2] * h4.z;
        dot += w[4 * e4 + 3] * h4.w;
      }
      if (j >= 256) { ndot[j - 256] = dot; nxg[j - 256] = xgc; }
      else if (j >= 128) { zb[j - 128] = xgc + dot; }
      __syncthreads();
      if (j < 128) {
        float r = sigm(xgc + dot);
        float z = sigm(zb[j]);
        float n = tanh_f(nxg[j] + r * ndot[j]);
        hreg = (1.f - z) * n + z * hreg;
        h_lds[j] = hreg;
      }
      __syncthreads();
      xgc = xgn;
    }
    if (j < 128) {
      if (b == 0) u_out[j] = hreg; else cmem_out[j] = hreg;
    }
  } else {
    const float* Wih = ((b == 2) ? enc_Wih : cenc_Wih) + 384 * 1024;
    const float* bih = ((b == 2) ? enc_bih : cenc_bih) + 384;
    const float* bhh = ((b == 2) ? enc_bhh : cenc_bhh) + 384;
    const float* crow = c_in + (long)(kT - 1) * 1024;
    float acc = bih[j];
    for (int k = 0; k < 1024; k += 4) {
      float4 cv = *(const float4*)&crow[k];
      float4 wv = *(const float4*)&Wih[j * 1024 + k];
      acc += cv.x * wv.x + cv.y * wv.y + cv.z * wv.z + cv.w * wv.w;
    }
    float bh = bhh[j];
    if (j >= 256) { ndot[j - 256] = bh; nxg[j - 256] = acc; }
    else if (j >= 128) { zb[j - 128] = acc + bh; }
    __syncthreads();
    if (j < 128) {
      float r = sigm(acc + bh);
      float z = sigm(zb[j]);
      float n = tanh_f(nxg[j] + r * ndot[j]);
      float h = (1.f - z) * n;
      if (b == 2) u_out[128 + j] = h; else cmem_out[128 + j] = h;
    }
  }
}

// ---------------- attention ----------------
__global__ __launch_bounds__(256) void attn_dots(
    const float* __restrict__ mem, const float* __restrict__ u, float* __restrict__ d) {
  __shared__ float us[256];
  int tid = threadIdx.x;
  us[tid] = u[tid];
  __syncthreads();
  int g = tid >> 3, l8 = tid & 7;
  int row = blockIdx.x * 32 + g;
  const float* mr = mem + (long)row * 256 + l8 * 32;
  float p = 0.f;
#pragma unroll
  for (int k = 0; k < 32; k += 4) {
    float4 m4 = *(const float4*)&mr[k];
    p += m4.x * us[l8 * 32 + k] + m4.y * us[l8 * 32 + k + 1] +
         m4.z * us[l8 * 32 + k + 2] + m4.w * us[l8 * 32 + k + 3];
  }
  p += __shfl_down(p, 4);
  p += __shfl_down(p, 2);
  p += __shfl_down(p, 1);
  if (l8 == 0) d[row] = p;
}

__global__ __launch_bounds__(1024) void attn_soft(
    const float* __restrict__ d, float* __restrict__ p, float* __restrict__ h_acc) {
  __shared__ float red[1024];
  int tid = threadIdx.x;
  float v[8];
  float mx = -1e30f;
#pragma unroll
  for (int i = 0; i < 8; i++) { v[i] = d[tid * 8 + i]; mx = fmaxf(mx, v[i]); }
  red[tid] = mx; __syncthreads();
  for (int s = 512; s > 0; s >>= 1) {
    if (tid < s) red[tid] = fmaxf(red[tid], red[tid + s]);
    __syncthreads();
  }
  mx = red[0]; __syncthreads();
  float sm = 0.f; float e[8];
#pragma unroll
  for (int i = 0; i < 8; i++) { e[i] = __expf(v[i] - mx); sm += e[i]; }
  red[tid] = sm; __syncthreads();
  for (int s = 512; s > 0; s >>= 1) {
    if (tid < s) red[tid] += red[tid + s];
    __syncthreads();
  }
  float rz = 1.f / red[0];
#pragma unroll
  for (int i = 0; i < 8; i++) p[tid * 8 + i] = e[i] * rz;
  if (tid < 256) h_acc[tid] = 0.f;   // re-zero every launch (stream-ordered before attn_h)
}

__global__ __launch_bounds__(256) void attn_h(
    const float* __restrict__ mem, const float* __restrict__ p, float* __restrict__ h_acc) {
  int tid = threadIdx.x;
  int r0 = blockIdx.x * 128;
  float acc = 0.f;
  for (int i = 0; i < 128; i++) acc += p[r0 + i] * mem[(long)(r0 + i) * 256 + tid];
  atomicAdd(&h_acc[tid], acc);
}

__global__ __launch_bounds__(128) void attn_o(
    const float* __restrict__ u, const float* __restrict__ h_acc,
    const float* __restrict__ know_W, const float* __restrict__ know_b,
    float* __restrict__ o) {
  __shared__ float uh[256];
  int tid = threadIdx.x;
  uh[tid] = u[tid] + h_acc[tid];
  uh[128 + tid] = u[128 + tid] + h_acc[128 + tid];
  __syncthreads();
  int row = blockIdx.x * 128 + tid;
  float acc = know_b[row];
  for (int k = 0; k < 256; k += 4) {
    float4 w4 = *(const float4*)&know_W[row * 256 + k];
    acc += w4.x * uh[k] + w4.y * uh[k + 1] + w4.z * uh[k + 2] + w4.w * uh[k + 3];
  }
  o[row] = acc;
}

__global__ __launch_bounds__(128) void attn_ov(
    const float* __restrict__ o, const float* __restrict__ Wih0, float* __restrict__ ov) {
  int row = blockIdx.x * 128 + threadIdx.x;
  float acc = 0.f;
  for (int k = 0; k < 1024; k += 4) {
    float4 w4 = *(const float4*)&Wih0[(long)row * 1024 + k];
    float4 o4 = *(const float4*)&o[k];
    acc += w4.x * o4.x + w4.y * o4.y + w4.z * o4.z + w4.w * o4.w;
  }
  ov[row] = acc;
}

// fold X[t][c] += v[c]
__global__ __launch_bounds__(256) void add_vec_rows(
    float* __restrict__ X, const float* __restrict__ v) {
  int t = blockIdx.x;
  int c = threadIdx.x * 8;
  float* xp = X + (long)t * 2048 + c;
  float4 a = *(const float4*)(xp);
  float4 b = *(const float4*)(xp + 4);
  float4 va = *(const float4*)(v + c);
  float4 vb = *(const float4*)(v + c + 4);
  a.x += va.x; a.y += va.y; a.z += va.z; a.w += va.w;
  b.x += vb.x; b.y += vb.y; b.z += vb.z; b.w += vb.w;
  *(float4*)(xp) = a;
  *(float4*)(xp + 4) = b;
}

// ---------------- LSTM chain (one direction per block, 256 threads, 1 wave/SIMD) ----------------
// Thread j owns gate rows {j, 256+j, 512+j, 768+j} = (i,f,g,o) of h-element j.
// Per-row 128 half2 weights: 44 in VGPR + 56 in AGPR (inline-asm pinned) + 28 in LDS.
// LDS weights: [row][32] u32 with XOR chunk swizzle (chunk c at slot c^(row&7)) -> b128 conflict-free.
static constexpr int RV = 44;   // e in [0,44)    VGPR
static constexpr int RA = 56;   // e in [44,100)  AGPR
static constexpr int RLB = 100; // LDS base e; e in [100,128) LDS (28 elems, 7 chunks)

__global__ __launch_bounds__(256, 1) void lstm_kernel(
    const unsigned* __restrict__ wprep,  // this layer: [dir][128][1024] half2-packed
    const float* __restrict__ xg,        // [T][2048], col = dir*1024 + row (biases folded)
    float* __restrict__ out) {           // [T][512], fwd cols 0:256, bwd 256:512
  int dir = blockIdx.x, j = threadIdx.x;   // j in [0,256)
  __shared__ unsigned wl[1024 * 32];       // 128 KB swizzled weight slab
  __shared__ unsigned h2v[2 * 128];        // packed h double buffer
  const unsigned* wp = wprep + dir * (128 * 1024);

  // fill LDS weight slab (e' in [0,28), row in [0,1024))
  for (int i = j; i < 1024 * 28; i += 256) {
    int e = i >> 10;          // 0..27
    int row = i & 1023;
    int c = e >> 2, q = e & 3;
    wl[row * 32 + (((c ^ (row & 7)) << 2) | q)] = wp[(RLB + e) * 1024 + row];
  }
  // VGPR weights
  unsigned wv0[RV], wv1[RV], wv2[RV], wv3[RV];
#pragma unroll
  for (int e = 0; e < RV; e++) {
    wv0[e] = wp[e * 1024 + j];
    wv1[e] = wp[e * 1024 + 256 + j];
    wv2[e] = wp[e * 1024 + 512 + j];
    wv3[e] = wp[e * 1024 + 768 + j];
  }
  // AGPR weights (pinned)
  unsigned wa0[RA], wa1[RA], wa2[RA], wa3[RA];
#pragma unroll
  for (int e = 0; e < RA; e++) {
    wa0[e] = to_agpr(wp[(RV + e) * 1024 + j]);
    wa1[e] = to_agpr(wp[(RV + e) * 1024 + 256 + j]);
    wa2[e] = to_agpr(wp[(RV + e) * 1024 + 512 + j]);
    wa3[e] = to_agpr(wp[(RV + e) * 1024 + 768 + j]);
  }
  if (j < 128) h2v[j] = 0u;
  float cst = 0.f;
  __syncthreads();

  const float* xp = xg + (dir ? 1024 : 0);
  const int t0 = dir ? (kT - 1) : 0;
  const int dt = dir ? -1 : 1;
  const int sw = j & 7;
  const int r0b = j * 32, r1b = (256 + j) * 32, r2b = (512 + j) * 32, r3b = (768 + j) * 32;

  float x0 = xp[(long)t0 * 2048 + j];
  float x1 = xp[(long)t0 * 2048 + 256 + j];
  float x2 = xp[(long)t0 * 2048 + 512 + j];
  float x3 = xp[(long)t0 * 2048 + 768 + j];

  for (int s = 0; s < kT; ++s) {
    int t = t0 + s * dt;
    float n0 = 0.f, n1 = 0.f, n2 = 0.f, n3 = 0.f;
    if (s + 1 < kT) {
      const float* xn = xp + (long)(t + dt) * 2048;
      n0 = xn[j]; n1 = xn[256 + j]; n2 = xn[512 + j]; n3 = xn[768 + j];
    }
    const unsigned* hb = &h2v[(s & 1) * 128];
    float a0 = x0, a1 = x1, a2 = x2, a3 = x3;
    float b0 = 0.f, b1 = 0.f, b2 = 0.f, b3 = 0.f;

    // ---- LDS weight section: e in [100,128), 7 chunks ----
#pragma unroll
    for (int c = 0; c < 7; ++c) {
      uint4 hh = *(const uint4*)&hb[RLB + c * 4];
      int sl = ((c ^ sw) << 2);
      uint4 q0 = *(const uint4*)&wl[r0b + sl];
      uint4 q1 = *(const uint4*)&wl[r1b + sl];
      uint4 q2 = *(const uint4*)&wl[r2b + sl];
      uint4 q3 = *(const uint4*)&wl[r3b + sl];
      a0 = fdot2u(q0.x, hh.x, a0); b0 = fdot2u(q0.y, hh.y, b0);
      a0 = fdot2u(q0.z, hh.z, a0); b0 = fdot2u(q0.w, hh.w, b0);
      a1 = fdot2u(q1.x, hh.x, a1); b1 = fdot2u(q1.y, hh.y, b1);
      a1 = fdot2u(q1.z, hh.z, a1); b1 = fdot2u(q1.w, hh.w, b1);
      a2 = fdot2u(q2.x, hh.x, a2); b2 = fdot2u(q2.y, hh.y, b2);
      a2 = fdot2u(q2.z, hh.z, a2); b2 = fdot2u(q2.w, hh.w, b2);
      a3 = fdot2u(q3.x, hh.x, a3); b3 = fdot2u(q3.y, hh.y, b3);
      a3 = fdot2u(q3.z, hh.z, a3); b3 = fdot2u(q3.w, hh.w, b3);
    }
    // ---- VGPR weight section: e in [0,44) ----
#pragma unroll
    for (int e4 = 0; e4 < RV / 4; ++e4) {
      uint4 hh = *(const uint4*)&hb[e4 * 4];
      a0 = fdot2u(wv0[4 * e4 + 0], hh.x, a0); b0 = fdot2u(wv0[4 * e4 + 1], hh.y, b0);
      a0 = fdot2u(wv0[4 * e4 + 2], hh.z, a0); b0 = fdot2u(wv0[4 * e4 + 3], hh.w, b0);
      a1 = fdot2u(wv1[4 * e4 + 0], hh.x, a1); b1 = fdot2u(wv1[4 * e4 + 1], hh.y, b1);
      a1 = fdot2u(wv1[4 * e4 + 2], hh.z, a1); b1 = fdot2u(wv1[4 * e4 + 3], hh.w, b1);
      a2 = fdot2u(wv2[4 * e4 + 0], hh.x, a2); b2 = fdot2u(wv2[4 * e4 + 1], hh.y, b2);
      a2 = fdot2u(wv2[4 * e4 + 2], hh.z, a2); b2 = fdot2u(wv2[4 * e4 + 3], hh.w, b2);
      a3 = fdot2u(wv3[4 * e4 + 0], hh.x, a3); b3 = fdot2u(wv3[4 * e4 + 1], hh.y, b3);
      a3 = fdot2u(wv3[4 * e4 + 2], hh.z, a3); b3 = fdot2u(wv3[4 * e4 + 3], hh.w, b3);
    }
    // ---- AGPR weight section: e in [44,100) ----
#pragma unroll
    for (int e4 = 0; e4 < RA / 4; ++e4) {
      uint4 hh = *(const uint4*)&hb[RV + e4 * 4];
      a0 = fdot2u(from_agpr(wa0[4 * e4 + 0]), hh.x, a0);
      b0 = fdot2u(from_agpr(wa0[4 * e4 + 1]), hh.y, b0);
      a0 = fdot2u(from_agpr(wa0[4 * e4 + 2]), hh.z, a0);
      b0 = fdot2u(from_agpr(wa0[4 * e4 + 3]), hh.w, b0);
      a1 = fdot2u(from_agpr(wa1[4 * e4 + 0]), hh.x, a1);
      b1 = fdot2u(from_agpr(wa1[4 * e4 + 1]), hh.y, b1);
      a1 = fdot2u(from_agpr(wa1[4 * e4 + 2]), hh.z, a1);
      b1 = fdot2u(from_agpr(wa1[4 * e4 + 3]), hh.w, b1);
      a2 = fdot2u(from_agpr(wa2[4 * e4 + 0]), hh.x, a2);
      b2 = fdot2u(from_agpr(wa2[4 * e4 + 1]), hh.y, b2);
      a2 = fdot2u(from_agpr(wa2[4 * e4 + 2]), hh.z, a2);
      b2 = fdot2u(from_agpr(wa2[4 * e4 + 3]), hh.w, b2);
      a3 = fdot2u(from_agpr(wa3[4 * e4 + 0]), hh.x, a3);
      b3 = fdot2u(from_agpr(wa3[4 * e4 + 1]), hh.y, b3);
      a3 = fdot2u(from_agpr(wa3[4 * e4 + 2]), hh.z, a3);
      b3 = fdot2u(from_agpr(wa3[4 * e4 + 3]), hh.w, b3);
    }

    float ig = sigm(a0 + b0);
    float fg = sigm(a1 + b1);
    float gg = tanh_f(a2 + b2);
    float og = sigm(a3 + b3);
    cst = fg * cst + ig * gg;
    float h = og * tanh_f(cst);
    out[(long)t * 512 + dir * 256 + j] = h;
    float hx = __shfl_xor(h, 1);
    if (!(j & 1)) h2v[((s + 1) & 1) * 128 + (j >> 1)] = pack_h2(h, hx);
    __syncthreads();
    x0 = n0; x1 = n1; x2 = n2; x3 = n3;
  }
}

// ---------------- final row softmax ----------------
__global__ __launch_bounds__(256) void softmax_rows(
    const float* __restrict__ logits, float* __restrict__ outp) {
  int t = blockIdx.x, tid = threadIdx.x;
  __shared__ float red[256];
  const float* lr = logits + (long)t * 4096;
  float v[16];
  float mx = -1e30f;
#pragma unroll
  for (int i = 0; i < 16; i++) { v[i] = lr[tid + 256 * i]; mx = fmaxf(mx, v[i]); }
  red[tid] = mx; __syncthreads();
  for (int s = 128; s > 0; s >>= 1) {
    if (tid < s) red[tid] = fmaxf(red[tid], red[tid + s]);
    __syncthreads();
  }
  mx = red[0]; __syncthreads();
  float sm = 0.f;
#pragma unroll
  for (int i = 0; i < 16; i++) { v[i] = __expf(v[i] - mx); sm += v[i]; }
  red[tid] = sm; __syncthreads();
  for (int s = 128; s > 0; s >>= 1) {
    if (tid < s) red[tid] += red[tid + s];
    __syncthreads();
  }
  float rz = 1.f / red[0];
#pragma unroll
  for (int i = 0; i < 16; i++) outp[(long)t * 4096 + tid + 256 * i] = v[i] * rz;
}

// ---------------- launch ----------------
extern "C" void kernel_launch(void* const* d_in, const int* in_sizes, int n_in,
                              void* d_out, int out_size, void* d_ws, size_t ws_size,
                              hipStream_t stream) {
  const float* c        = (const float*)d_in[0];
  const float* memory   = (const float*)d_in[1];
  const float* enc_Wih  = (const float*)d_in[2];
  const float* enc_Whh  = (const float*)d_in[3];
  const float* enc_bih  = (const float*)d_in[4];
  const float* enc_bhh  = (const float*)d_in[5];
  const float* cenc_Wih = (const float*)d_in[6];
  const float* cenc_Whh = (const float*)d_in[7];
  const float* cenc_bih = (const float*)d_in[8];
  const float* cenc_bhh = (const float*)d_in[9];
  const float* know_W   = (const float*)d_in[10];
  const float* know_b   = (const float*)d_in[11];
  const float* l0_Wih   = (const float*)d_in[12];
  const float* l0_Whh   = (const float*)d_in[13];
  const float* l0_bih   = (const float*)d_in[14];
  const float* l0_bhh   = (const float*)d_in[15];
  const float* l1_Wih   = (const float*)d_in[16];
  const float* l1_Whh   = (const float*)d_in[17];
  const float* l1_bih   = (const float*)d_in[18];
  const float* l1_bhh   = (const float*)d_in[19];
  const float* out_W    = (const float*)d_in[20];
  const float* out_b    = (const float*)d_in[21];

  float* ws = (float*)d_ws;
  float* outp = (float*)d_out;

  float* xgg   = ws;                  // 1,572,864   [T][768]
  float* cW    = ws + 1572864;        // 4,194,304   [T][2048]
  float* wcat  = ws + 5767168;        //   786,432
  float* l0out = ws + 6553600;        // 1,048,576   [T][512]
  float* xg1   = ws + 7602176;        // 4,194,304   [T][2048]
  unsigned* wprep = (unsigned*)(ws + 11796480);  // 524,288 u32
  float* bcat  = ws + 12320768;       // 768
  float* bias0 = ws + 12321536;       // 2048
  float* bias1 = ws + 12323584;       // 2048
  float* u_vec = ws + 12325632;       // 256
  float* d_att = ws + 12325888;       // 8192
  float* p_att = ws + 12334080;       // 8192
  float* h_acc = ws + 12342272;       // 256
  float* o_vec = ws + 12342528;       // 1024
  float* ov    = ws + 12343552;       // 2048
  float* l1out = ws + 12345600;       // 1,048,576
  float* logits = ws;                 // 8,388,608   aliases xgg/cW/wcat/l0out/part of xg1

  prep_kernel<<<512, 256, 0, stream>>>(enc_Wih, enc_bih, cenc_Wih, cenc_bih,
                                       l0_Whh, l1_Whh, l0_bih, l0_bhh, l1_bih, l1_bhh,
                                       wcat, bcat, bias0, bias1, wprep);
  gemm_bt<<<dim3(768 / 64, 2048 / 64), 256, 0, stream>>>(c, wcat, bcat, xgg, 2048, 768, 1024);
  gemm_bt<<<dim3(2048 / 64, 2048 / 64), 256, 0, stream>>>(c, l0_Wih, bias0, cW, 2048, 2048, 1024);
  gru_kernel<<<4, 384, 0, stream>>>(xgg, c, enc_Wih, enc_Whh, enc_bih, enc_bhh,
                                    cenc_Wih, cenc_Whh, cenc_bih, cenc_bhh,
                                    u_vec, outp + kOUT_ELEMS);
  attn_dots<<<256, 256, 0, stream>>>(memory, u_vec, d_att);
  attn_soft<<<1, 1024, 0, stream>>>(d_att, p_att, h_acc);
  attn_h<<<64, 256, 0, stream>>>(memory, p_att, h_acc);
  attn_o<<<8, 128, 0, stream>>>(u_vec, h_acc, know_W, know_b, o_vec);
  attn_ov<<<16, 128, 0, stream>>>(o_vec, l0_Wih, ov);
  add_vec_rows<<<2048, 256, 0, stream>>>(cW, ov);
  lstm_kernel<<<2, 256, 0, stream>>>(wprep, cW, l0out);
  gemm_bt<<<dim3(2048 / 64, 2048 / 64), 256, 0, stream>>>(l0out, l1_Wih, bias1, xg1, 2048, 2048, 512);
  lstm_kernel<<<2, 256, 0, stream>>>(wprep + 2 * 131072, xg1, l1out);
  gemm_bt<<<dim3(4096 / 64, 2048 / 64), 256, 0, stream>>>(l1out, out_W, out_b, logits, 2048, 4096, 512);
  softmax_rows<<<2048, 256, 0, stream>>>(logits, outp);
}